// Round 1
// baseline (478.802 us; speedup 1.0000x reference)
//
#include <hip/hip_runtime.h>

typedef unsigned short u16;
typedef u16 u16x8 __attribute__((ext_vector_type(8)));
typedef u16 u16x4 __attribute__((ext_vector_type(4)));
typedef __bf16 bf16x8 __attribute__((ext_vector_type(8)));
typedef float f32x4 __attribute__((ext_vector_type(4)));

#define DEVI static __device__ __forceinline__

DEVI float b2f(u16 u){ union { unsigned u; float f; } c; c.u = ((unsigned)u) << 16; return c.f; }
DEVI u16 f2b(float f){ union { float f; unsigned u; } c; c.f = f;
  unsigned r = c.u + 0x7fffu + ((c.u >> 16) & 1u); return (u16)(r >> 16); }
DEVI void gload16(const void* g, void* l){
  __builtin_amdgcn_global_load_lds((const __attribute__((address_space(1))) void*)g,
                                   (__attribute__((address_space(3))) void*)l, 16, 0, 0);
}
DEVI f32x4 MFMA(bf16x8 a, bf16x8 b, f32x4 c){
  return __builtin_amdgcn_mfma_f32_16x16x32_bf16(a, b, c, 0, 0, 0);
}

// Problem constants
// B=2, L=2048, HID=2048, H=16, HKV=8, D=128, CHUNK=64, NC=32, TOK=4096
// Workspace layout (bytes)
constexpr size_t OFF_HB  = 0;                                   // h bf16 [4096][2048]
constexpr size_t OFF_WCT = OFF_HB  + (size_t)4096*2048*2;       // WcatT bf16 [4224][2048] (Wq|Wk|Wv|Wg1|pad)^T
constexpr size_t OFF_WOT = OFF_WCT + (size_t)4224*2048*2;       // WoT bf16 [2048][2048]
constexpr size_t OFF_QKV = OFF_WOT + (size_t)2048*2048*2;       // QKV bf16 [4096][4096] (q|k|v)
constexpr size_t OFF_G1  = OFF_QKV + (size_t)4096*4096*2;       // G1 f32 [4096][16]
constexpr size_t OFF_G   = OFF_G1  + (size_t)4096*16*4;         // g f32 [4096][1024]
constexpr size_t OFF_EB  = OFF_G   + (size_t)4096*1024*4;       // exp(b) bf16 [4096][1024]
constexpr size_t OFF_KD  = OFF_EB  + (size_t)4096*1024*2;       // k*exp(-b) bf16 [4096][1024]
constexpr size_t OFF_T   = OFF_KD  + (size_t)4096*1024*2;       // T bf16 [2][8][32][128 d][128 e]
constexpr size_t OFF_DV  = OFF_T   + (size_t)2*8*32*128*128*2;  // Dvec f32 [2][8][32][128]
constexpr size_t OFF_SP  = OFF_DV  + (size_t)2*8*32*128*4;      // S_prefix bf16 [2][8][32][128 e][128 d]
constexpr size_t OFF_ON  = OFF_SP  + (size_t)2*8*32*128*128*2;  // o_normed bf16 [4096][2048]
// total = OFF_ON + 16777216 = 160432128 bytes (~153 MiB)

// ---------------- conversion ----------------
__global__ __launch_bounds__(256) void k_conv_h(const float* __restrict__ h,
                                                u16* __restrict__ hb, u16* __restrict__ padz){
  int idx = blockIdx.x*256 + threadIdx.x, stride = gridDim.x*256;
  for (int i = idx; i < 4096*2048/4; i += stride){
    float4 v = ((const float4*)h)[i];
    u16x4 o; o[0]=f2b(v.x); o[1]=f2b(v.y); o[2]=f2b(v.z); o[3]=f2b(v.w);
    ((u16x4*)hb)[i] = o;
  }
  for (int i = idx; i < 112*2048/4; i += stride){ u16x4 z = {0,0,0,0}; ((u16x4*)padz)[i] = z; }
}

// dst[(rowOff+n)*pitch + k] = bf16(src[k][n]) ; K multiple of 64
__global__ __launch_bounds__(256) void k_transpose(const float* __restrict__ src, u16* __restrict__ dst,
                                                   int K, int N, int rowOff, int pitch){
  __shared__ float tile[64][65];
  int kb = blockIdx.y*64, nb = blockIdx.x*64;
  int t = threadIdx.x, x = t & 63, y0 = t >> 6;
#pragma unroll
  for (int i = 0; i < 16; i++){
    int y = y0 + i*4, k = kb + y, n = nb + x;
    tile[y][x] = (n < N) ? src[(size_t)k*N + n] : 0.f;
  }
  __syncthreads();
#pragma unroll
  for (int i = 0; i < 16; i++){
    int y = y0 + i*4, n = nb + y, k = kb + x;
    if (n < N) dst[(size_t)(rowOff + n)*pitch + k] = f2b(tile[x][y]);
  }
}

// ---------------- GEMM (m97 structure): C[m][n] = sum_k A[m][k]*Bt[n][k] ----------------
// MODE 0: QKV+G1 projection epilogue ; MODE 1: fp32 output store
template<int MODE>
__global__ __launch_bounds__(256) void k_gemm(const u16* __restrict__ A, const u16* __restrict__ Bt,
                                              u16* __restrict__ Cq, float* __restrict__ Cg1,
                                              float* __restrict__ Cf,
                                              const float* __restrict__ bq, const float* __restrict__ bk,
                                              const float* __restrict__ bv){
  constexpr int Kd = 2048;
  __shared__ u16 lA[128*32];
  __shared__ u16 lB[128*32];
  int nt = blockIdx.x, mt = blockIdx.y;
  int t = threadIdx.x, w = t >> 6, l = t & 63;
  size_t aBase = (size_t)(mt*128 + (t>>2))*Kd + (t&3)*8;
  size_t bBase = (size_t)(nt*128 + (t>>2))*Kd + (t&3)*8;
  int wm = (w>>1)*64, wn = (w&1)*64;
  f32x4 acc[4][4] = {};
  u16* lA0 = &lA[w*512]; u16* lA1 = &lA[2048 + w*512];
  u16* lB0 = &lB[w*512]; u16* lB1 = &lB[2048 + w*512];
  for (int k0 = 0; k0 < Kd; k0 += 32){
    gload16(A + aBase + k0, lA0);
    gload16(A + aBase + (size_t)64*Kd + k0, lA1);
    gload16(Bt + bBase + k0, lB0);
    gload16(Bt + bBase + (size_t)64*Kd + k0, lB1);
    __syncthreads();
    bf16x8 af[4], bfv[4];
#pragma unroll
    for (int mi = 0; mi < 4; mi++) af[mi]  = *(const bf16x8*)&lA[(wm + mi*16 + (l&15))*32 + (l>>4)*8];
#pragma unroll
    for (int ni = 0; ni < 4; ni++) bfv[ni] = *(const bf16x8*)&lB[(wn + ni*16 + (l&15))*32 + (l>>4)*8];
#pragma unroll
    for (int mi = 0; mi < 4; mi++)
#pragma unroll
      for (int ni = 0; ni < 4; ni++)
        acc[mi][ni] = MFMA(af[mi], bfv[ni], acc[mi][ni]);
    __syncthreads();
  }
  int iLoc = (l>>4)*4, jc = l & 15;
  if (MODE == 0){
#pragma unroll
    for (int ni = 0; ni < 4; ni++){
      int n0 = nt*128 + wn + ni*16;
      int n = n0 + jc;
      int kind; float bias = 0.f;
      if (n0 < 2048){ kind = 0; bias = bq[n]; }
      else if (n0 < 3072){ kind = 1; bias = bk[n - 2048]; }
      else if (n0 < 4096){ kind = 2; bias = bv[n - 3072]; }
      else if (n0 == 4096){ kind = 3; }
      else { kind = 4; }
      if (kind == 4) continue;
#pragma unroll
      for (int mi = 0; mi < 4; mi++){
        int m = mt*128 + wm + mi*16 + iLoc;
#pragma unroll
        for (int rr = 0; rr < 4; rr++){
          float x = acc[mi][ni][rr];
          int row = m + rr;
          if (kind == 0)      Cq[(size_t)row*4096 + n] = f2b(fmaxf(x + bias, 0.f) * 0.08838834764831845f);
          else if (kind == 1) Cq[(size_t)row*4096 + n] = f2b(fmaxf(x + bias, 0.f));
          else if (kind == 2) Cq[(size_t)row*4096 + n] = f2b(x + bias);
          else                Cg1[(size_t)row*16 + (n - 4096)] = x;
        }
      }
    }
  } else {
#pragma unroll
    for (int ni = 0; ni < 4; ni++){
      int n = nt*128 + wn + ni*16 + jc;
#pragma unroll
      for (int mi = 0; mi < 4; mi++){
        int m = mt*128 + wm + mi*16 + iLoc;
#pragma unroll
        for (int rr = 0; rr < 4; rr++) Cf[(size_t)(m+rr)*2048 + n] = acc[mi][ni][rr];
      }
    }
  }
}

// ---------------- gates: g = logsigmoid(G1 @ Wg2 + bg2)/16 ----------------
__global__ __launch_bounds__(256) void k_gates(const float* __restrict__ G1, const float* __restrict__ Wg2,
                                               const float* __restrict__ bg2, float* __restrict__ g){
  __shared__ float w2[16*1024];
  __shared__ float bb[1024];
  __shared__ float g1l[256];
  int t = threadIdx.x;
  for (int i = t; i < 4096; i += 256) ((float4*)w2)[i] = ((const float4*)Wg2)[i];
  ((float4*)bb)[t] = ((const float4*)bg2)[t];
  int tok0 = blockIdx.x*16;
  g1l[t] = G1[(size_t)tok0*16 + t];
  __syncthreads();
  int c0 = t*4;
  for (int tk = 0; tk < 16; tk++){
    float4 a = *(const float4*)&bb[c0];
#pragma unroll
    for (int r = 0; r < 16; r++){
      float gv = g1l[tk*16 + r];
      float4 wr = *(const float4*)&w2[r*1024 + c0];
      a.x += gv*wr.x; a.y += gv*wr.y; a.z += gv*wr.z; a.w += gv*wr.w;
    }
    float4 o;
    o.x = (fminf(a.x,0.f) - log1pf(expf(-fabsf(a.x)))) * 0.0625f;
    o.y = (fminf(a.y,0.f) - log1pf(expf(-fabsf(a.y)))) * 0.0625f;
    o.z = (fminf(a.z,0.f) - log1pf(expf(-fabsf(a.z)))) * 0.0625f;
    o.w = (fminf(a.w,0.f) - log1pf(expf(-fabsf(a.w)))) * 0.0625f;
    *(float4*)&g[(size_t)(tok0+tk)*1024 + c0] = o;
  }
}

// ---------------- phase A: cumsum gates, k_, eb, T_c = kend^T @ v, Dvec ----------------
__global__ __launch_bounds__(256) void k_phaseA(const float* __restrict__ g, const u16* __restrict__ QKV,
                                                u16* __restrict__ eb, u16* __restrict__ kd,
                                                u16* __restrict__ T, float* __restrict__ Dv){
  __shared__ float gb[64*128];     // becomes cumsum b in-place
  __shared__ u16 keT[128*72];      // kend^T [d][c]
  __shared__ u16 vT [128*72];      // v^T    [e][c]
  int c = blockIdx.x, kvh = blockIdx.y, b = blockIdx.z;
  int t = threadIdx.x;
  int tok0 = b*2048 + c*64;
#pragma unroll
  for (int r = 0; r < 8; r++){
    int idx4 = r*256 + t;
    int i = idx4 >> 5, c4 = idx4 & 31;
    ((float4*)gb)[i*32 + c4] = *(const float4*)&g[(size_t)(tok0+i)*1024 + kvh*128 + c4*4];
  }
  __syncthreads();
  if (t < 128){
    float run = 0.f;
    for (int i = 0; i < 64; i++){ run += gb[i*128 + t]; gb[i*128 + t] = run; }
    Dv[((size_t)(b*8+kvh)*32 + c)*128 + t] = expf(run);
  }
  __syncthreads();
  int d0 = (t&15)*8;
  float blast[8];
#pragma unroll
  for (int j = 0; j < 8; j++) blast[j] = gb[63*128 + d0 + j];
#pragma unroll
  for (int r = 0; r < 4; r++){
    int i = (t>>4) + r*16;
    u16x8 kv_ = *(const u16x8*)&QKV[(size_t)(tok0+i)*4096 + 2048 + kvh*128 + d0];
    u16x8 vv  = *(const u16x8*)&QKV[(size_t)(tok0+i)*4096 + 3072 + kvh*128 + d0];
    u16x8 ebv, kdv;
#pragma unroll
    for (int j = 0; j < 8; j++){
      float bcur = gb[i*128 + d0 + j];
      float kf = b2f(kv_[j]);
      ebv[j] = f2b(expf(bcur));
      kdv[j] = f2b(kf * expf(-bcur));
      keT[(d0+j)*72 + i] = f2b(kf * expf(blast[j] - bcur));
      vT [(d0+j)*72 + i] = vv[j];
    }
    *(u16x8*)&eb[(size_t)(tok0+i)*1024 + kvh*128 + d0] = ebv;
    *(u16x8*)&kd[(size_t)(tok0+i)*1024 + kvh*128 + d0] = kdv;
  }
  __syncthreads();
  int w = t>>6, l = t&63;
  f32x4 acc[2][8] = {};
#pragma unroll
  for (int ks = 0; ks < 2; ks++){
    bf16x8 af[2];
#pragma unroll
    for (int ti = 0; ti < 2; ti++)
      af[ti] = *(const bf16x8*)&keT[(w*32 + ti*16 + (l&15))*72 + ks*32 + (l>>4)*8];
#pragma unroll
    for (int tj = 0; tj < 8; tj++){
      bf16x8 bf_ = *(const bf16x8*)&vT[(tj*16 + (l&15))*72 + ks*32 + (l>>4)*8];
#pragma unroll
      for (int ti = 0; ti < 2; ti++) acc[ti][tj] = MFMA(af[ti], bf_, acc[ti][tj]);
    }
  }
  size_t tbase = ((size_t)(b*8+kvh)*32 + c)*16384;
#pragma unroll
  for (int ti = 0; ti < 2; ti++)
#pragma unroll
    for (int tj = 0; tj < 8; tj++)
#pragma unroll
      for (int rr = 0; rr < 4; rr++){
        int d = w*32 + ti*16 + (l>>4)*4 + rr, e = tj*16 + (l&15);
        T[tbase + d*128 + e] = f2b(acc[ti][tj][rr]);
      }
}

// ---------------- phase B: sequential scan over chunks, write transposed prefix states ----------------
__global__ __launch_bounds__(256) void k_phaseB(const u16* __restrict__ T, const float* __restrict__ Dv,
                                                u16* __restrict__ SP){
  __shared__ u16 sl[16*128];
  int es = blockIdx.x, kvh = blockIdx.y, b = blockIdx.z;
  int t = threadIdx.x;
  size_t bh = (size_t)(b*8 + kvh);
  float S[8] = {0,0,0,0,0,0,0,0};
  for (int c = 0; c < 32; c++){
#pragma unroll
    for (int r = 0; r < 8; r++){
      int idx = r*256 + t, d = idx>>4, el = idx&15;
      sl[el*128 + d] = f2b(S[r]);
    }
    __syncthreads();
    size_t spb = (bh*32 + c)*16384 + (size_t)es*2048;
    *(u16x8*)&SP[spb + t*8] = *(const u16x8*)&sl[t*8];
    size_t tb  = (bh*32 + c)*16384;
    size_t dvb = (bh*32 + c)*128;
#pragma unroll
    for (int r = 0; r < 8; r++){
      int idx = r*256 + t, d = idx>>4, el = idx&15;
      float tv = b2f(T[tb + d*128 + es*16 + el]);
      S[r] = S[r]*Dv[dvb + d] + tv;
    }
    __syncthreads();
  }
}

// ---------------- phase C: scores + o = A@v + q_@S, RMSNorm, write o_normed ----------------
__global__ __launch_bounds__(256) void k_phaseC(const u16* __restrict__ QKV, const u16* __restrict__ eb,
                                                const u16* __restrict__ kd, const u16* __restrict__ SP,
                                                const float* __restrict__ gnw, u16* __restrict__ onrm){
  __shared__ u16 kl[64*128];   // k_ chunk, XOR-swizzled rows
  __shared__ u16 sl[64*72];    // masked scores
  __shared__ u16 vT[128*72];   // v^T [e][j]
  int c = blockIdx.x, h = blockIdx.y, b = blockIdx.z;
  int kvh = h >> 1;
  int t = threadIdx.x, w = t>>6, l = t&63;
  int tok0 = b*2048 + c*64;
  // stage k_ with pre-swizzled global source (LDS linear dest)
#pragma unroll
  for (int is = 0; is < 4; is++){
    int row = (t>>4) + is*16;
    int d0s = 8*((t&15) ^ (row&7));
    gload16(&kd[(size_t)(tok0+row)*1024 + kvh*128 + d0s], &kl[is*2048 + w*512]);
  }
  // v transpose into LDS
  int d0v = (t&15)*8;
#pragma unroll
  for (int r = 0; r < 4; r++){
    int i = (t>>4) + r*16;
    u16x8 vv = *(const u16x8*)&QKV[(size_t)(tok0+i)*4096 + 3072 + kvh*128 + d0v];
#pragma unroll
    for (int jj = 0; jj < 8; jj++) vT[(d0v+jj)*72 + i] = vv[jj];
  }
  // q_ fragments in registers
  bf16x8 aq[4];
  {
    int i = w*16 + (l&15);
#pragma unroll
    for (int kt = 0; kt < 4; kt++){
      int dq = kt*32 + (l>>4)*8;
      u16x8 qv = *(const u16x8*)&QKV[(size_t)(tok0+i)*4096 + h*128 + dq];
      u16x8 ev = *(const u16x8*)&eb[(size_t)(tok0+i)*1024 + kvh*128 + dq];
      u16x8 o;
#pragma unroll
      for (int jj = 0; jj < 8; jj++) o[jj] = f2b(b2f(qv[jj]) * b2f(ev[jj]));
      aq[kt] = __builtin_bit_cast(bf16x8, o);
    }
  }
  __syncthreads();
  // scores: A[i][j] = sum_d q_[i][d] k_[j][d]
  f32x4 accs[4] = {};
#pragma unroll
  for (int kt = 0; kt < 4; kt++){
#pragma unroll
    for (int jt = 0; jt < 4; jt++){
      int j = jt*16 + (l&15);
      int byte_ = j*256 + ((2*(kt*32 + (l>>4)*8)) ^ ((j&7)<<4));
      bf16x8 bk_ = *(const bf16x8*)((const char*)kl + byte_);
      accs[jt] = MFMA(aq[kt], bk_, accs[jt]);
    }
  }
  // causal mask + store scores
#pragma unroll
  for (int jt = 0; jt < 4; jt++)
#pragma unroll
    for (int rr = 0; rr < 4; rr++){
      int i = w*16 + (l>>4)*4 + rr;
      int j = jt*16 + (l&15);
      sl[i*72 + j] = f2b((i >= j) ? accs[jt][rr] : 0.f);
    }
  // o = q_ @ S  (S prefix, transposed layout [e][d]) + A @ v
  f32x4 acco[8] = {};
  size_t spb = ((size_t)(b*8+kvh)*32 + c)*16384;
#pragma unroll
  for (int kt = 0; kt < 4; kt++){
#pragma unroll
    for (int et = 0; et < 8; et++){
      int e = et*16 + (l&15);
      int dd = kt*32 + (l>>4)*8;
      bf16x8 bs = *(const bf16x8*)&SP[spb + (size_t)e*128 + dd];
      acco[et] = MFMA(aq[kt], bs, acco[et]);
    }
  }
#pragma unroll
  for (int kt2 = 0; kt2 < 2; kt2++){
    int i = w*16 + (l&15);
    bf16x8 as = *(const bf16x8*)&sl[i*72 + kt2*32 + (l>>4)*8];
#pragma unroll
    for (int et = 0; et < 8; et++){
      bf16x8 bv_ = *(const bf16x8*)&vT[(et*16 + (l&15))*72 + kt2*32 + (l>>4)*8];
      acco[et] = MFMA(as, bv_, acco[et]);
    }
  }
  // RMSNorm over head_dim, write o_normed bf16
  float gw[8];
#pragma unroll
  for (int et = 0; et < 8; et++) gw[et] = gnw[et*16 + (l&15)];
#pragma unroll
  for (int rr = 0; rr < 4; rr++){
    int i = w*16 + (l>>4)*4 + rr;
    float ss = 0.f;
#pragma unroll
    for (int et = 0; et < 8; et++){ float x = acco[et][rr]; ss += x*x; }
    ss += __shfl_xor(ss, 1); ss += __shfl_xor(ss, 2);
    ss += __shfl_xor(ss, 4); ss += __shfl_xor(ss, 8);
    float sc = rsqrtf(ss*(1.f/128.f) + 1e-5f);
#pragma unroll
    for (int et = 0; et < 8; et++){
      int e = et*16 + (l&15);
      onrm[(size_t)(tok0+i)*2048 + h*128 + e] = f2b(acco[et][rr]*sc*gw[et]);
    }
  }
}

extern "C" void kernel_launch(void* const* d_in, const int* in_sizes, int n_in,
                              void* d_out, int out_size, void* d_ws, size_t ws_size,
                              hipStream_t stream){
  (void)in_sizes; (void)n_in; (void)out_size; (void)ws_size;
  const float* h   = (const float*)d_in[0];
  const float* Wq  = (const float*)d_in[1];
  const float* bq  = (const float*)d_in[2];
  const float* Wk  = (const float*)d_in[3];
  const float* bk  = (const float*)d_in[4];
  const float* Wv  = (const float*)d_in[5];
  const float* bv  = (const float*)d_in[6];
  const float* Wg1 = (const float*)d_in[7];
  const float* Wg2 = (const float*)d_in[8];
  const float* bg2 = (const float*)d_in[9];
  const float* gnw = (const float*)d_in[10];
  const float* Wo  = (const float*)d_in[11];
  float* out = (float*)d_out;
  char* ws = (char*)d_ws;
  u16*   hb   = (u16*)  (ws + OFF_HB);
  u16*   wct  = (u16*)  (ws + OFF_WCT);
  u16*   wot  = (u16*)  (ws + OFF_WOT);
  u16*   qkv  = (u16*)  (ws + OFF_QKV);
  float* g1   = (float*)(ws + OFF_G1);
  float* gbuf = (float*)(ws + OFF_G);
  u16*   ebuf = (u16*)  (ws + OFF_EB);
  u16*   kdb  = (u16*)  (ws + OFF_KD);
  u16*   Tb   = (u16*)  (ws + OFF_T);
  float* Dvb  = (float*)(ws + OFF_DV);
  u16*   SPb  = (u16*)  (ws + OFF_SP);
  u16*   onb  = (u16*)  (ws + OFF_ON);

  k_conv_h<<<2048, 256, 0, stream>>>(h, hb, wct + (size_t)4112*2048);
  k_transpose<<<dim3(32,32), 256, 0, stream>>>(Wq,  wct, 2048, 2048,    0, 2048);
  k_transpose<<<dim3(16,32), 256, 0, stream>>>(Wk,  wct, 2048, 1024, 2048, 2048);
  k_transpose<<<dim3(16,32), 256, 0, stream>>>(Wv,  wct, 2048, 1024, 3072, 2048);
  k_transpose<<<dim3( 1,32), 256, 0, stream>>>(Wg1, wct, 2048,   16, 4096, 2048);
  k_transpose<<<dim3(32,32), 256, 0, stream>>>(Wo,  wot, 2048, 2048,    0, 2048);
  k_gemm<0><<<dim3(33,32), 256, 0, stream>>>(hb, wct, qkv, g1, nullptr, bq, bk, bv);
  k_gates<<<256, 256, 0, stream>>>(g1, Wg2, bg2, gbuf);
  k_phaseA<<<dim3(32,8,2), 256, 0, stream>>>(gbuf, qkv, ebuf, kdb, Tb, Dvb);
  k_phaseB<<<dim3(8,8,2), 256, 0, stream>>>(Tb, Dvb, SPb);
  k_phaseC<<<dim3(32,16,2), 256, 0, stream>>>(qkv, ebuf, kdb, SPb, gnw, onb);
  k_gemm<1><<<dim3(16,32), 256, 0, stream>>>(onb, wot, nullptr, nullptr, out, nullptr, nullptr, nullptr);
}